// Round 1
// baseline (2033.732 us; speedup 1.0000x reference)
//
#include <hip/hip_runtime.h>

#define N_NODES 16384
#define N_EDGES 1048576
#define D_IN 768
#define D_H 128
#define H_LSTM 64
#define S_CHUNK 128
#define NCHUNK (N_NODES / S_CHUNK)   // 128
#define WARMUP 256

static_assert(NCHUNK == 128, "lstm kernel assumes 128 chunks");

__device__ __forceinline__ float sigm_f(float x) { return 1.0f / (1.0f + __expf(-x)); }
__device__ __forceinline__ float tanh_f(float x) {
    float e = __expf(2.0f * x);
    return 1.0f - 2.0f / (e + 1.0f);
}
__device__ __forceinline__ float bcastlane(float v, int l) {
    return __int_as_float(__builtin_amdgcn_readlane(__float_as_int(v), l));
}

// ---------------- graph preprocessing: counting sort of edges by target ----------------

__global__ __launch_bounds__(256) void k_hist(const int* __restrict__ col,
        const float* __restrict__ w, int* __restrict__ cnt, float* __restrict__ deg) {
    int e = blockIdx.x * 256 + threadIdx.x;
    int c = col[e];
    atomicAdd(&cnt[c], 1);
    atomicAdd(&deg[c], w[e]);
}

__global__ __launch_bounds__(1024) void k_scan(const int* __restrict__ cnt,
        const float* __restrict__ deg, int* __restrict__ off, float* __restrict__ dis) {
    __shared__ int part[1024];
    int t = threadIdx.x;
    int base = t * 16;
    int loc[16];
    int sum = 0;
    #pragma unroll
    for (int i = 0; i < 16; i++) { loc[i] = sum; sum += cnt[base + i]; }
    part[t] = sum;
    __syncthreads();
    for (int ofs = 1; ofs < 1024; ofs <<= 1) {
        int add = (t >= ofs) ? part[t - ofs] : 0;
        __syncthreads();
        part[t] += add;
        __syncthreads();
    }
    int excl = part[t] - sum;
    #pragma unroll
    for (int i = 0; i < 16; i++) off[base + i] = excl + loc[i];
    if (t == 1023) off[N_NODES] = part[1023];
    #pragma unroll
    for (int i = 0; i < 16; i++) {
        float d = deg[base + i];
        dis[base + i] = (d > 0.0f) ? rsqrtf(d) : 0.0f;
    }
}

__global__ __launch_bounds__(256) void k_scatter(const int* __restrict__ row,
        const int* __restrict__ col, const float* __restrict__ w,
        const int* __restrict__ off, int* __restrict__ cur,
        const float* __restrict__ dis, int* __restrict__ srow, float* __restrict__ snorm) {
    int e = blockIdx.x * 256 + threadIdx.x;
    int c = col[e], r = row[e];
    int p = off[c] + atomicAdd(&cur[c], 1);
    srow[p] = r;
    snorm[p] = dis[r] * w[e] * dis[c];
}

// ---------------- GEMM: C[M][N] = A[M][K] @ W[N][K]^T (+ b1 + b2) ----------------
// wave-per-row; A rows staged in LDS, W streamed from L2 (fully cached)

template <int K, int N>
__global__ __launch_bounds__(256) void k_gemm_rows(const float* __restrict__ A,
        const float* __restrict__ W, const float* __restrict__ b1,
        const float* __restrict__ b2, float* __restrict__ C) {
    __shared__ float arow[4][K];
    int blk = blockIdx.x, tid = threadIdx.x;
    const float4* Ag = (const float4*)(A + (size_t)blk * 4 * K);
    float4* As = (float4*)&arow[0][0];
    for (int i = tid; i < K; i += 256) As[i] = Ag[i];
    __syncthreads();
    int wv = tid >> 6, lane = tid & 63;
    size_t rowi = (size_t)blk * 4 + wv;
    constexpr int CPL = N / 64;
    float acc[CPL];
    #pragma unroll
    for (int s = 0; s < CPL; s++) acc[s] = 0.0f;
    for (int k = 0; k < K; k += 4) {
        float4 a = *(const float4*)&arow[wv][k];
        #pragma unroll
        for (int s = 0; s < CPL; s++) {
            float4 w4 = *(const float4*)&W[(size_t)(lane + 64 * s) * K + k];
            acc[s] += a.x * w4.x + a.y * w4.y + a.z * w4.z + a.w * w4.w;
        }
    }
    #pragma unroll
    for (int s = 0; s < CPL; s++) {
        int c = lane + 64 * s;
        float v = acc[s];
        if (b1) v += b1[c];
        if (b2) v += b2[c];
        C[rowi * N + c] = v;
    }
}

// ---------------- GCN aggregation: one block per target node ----------------

__global__ __launch_bounds__(128) void k_conv(const float* __restrict__ xl,
        const int* __restrict__ srow, const float* __restrict__ snorm,
        const int* __restrict__ off, const float* __restrict__ bias,
        float* __restrict__ out) {
    int n = blockIdx.x, d = threadIdx.x;
    int p0 = off[n], p1 = off[n + 1];
    float acc = 0.0f;
    for (int p = p0; p < p1; p++) {
        int r = srow[p];
        float nm = snorm[p];
        acc += nm * xl[(size_t)r * 128 + d];
    }
    out[(size_t)n * 128 + d] = fmaxf(acc + bias[d], 0.0f);
}

// ---------------- chunked bidirectional LSTM ----------------
// grid = 256 blocks: blocks 0..127 forward chunks, 128..255 backward chunks.
// 4 waves per block: wave w computes gate-type w (i,f,g,o) for all 64 units.
// Whh row per thread lives in 64 VGPRs; h broadcast via v_readlane; one barrier/step.

__global__ __launch_bounds__(256) void k_lstm(const float* __restrict__ gpf,
        const float* __restrict__ gpb, const float* __restrict__ Whh_f,
        const float* __restrict__ Whh_b, float* __restrict__ hf, float* __restrict__ hb) {
    int b = blockIdx.x;
    int dir = b >> 7;
    int ch = b & 127;
    const float* gpre = dir ? gpb : gpf;
    const float* Whh = dir ? Whh_b : Whh_f;
    float* hout = dir ? hb : hf;
    int tid = threadIdx.x, lane = tid & 63, wv = tid >> 6;
    float wreg[64];
    #pragma unroll
    for (int k = 0; k < 64; k++) wreg[k] = Whh[tid * 64 + k];
    __shared__ float act[2][256];
    float c = 0.0f, h = 0.0f;
    int outLo = ch * S_CHUNK;
    int t, nsteps, tstep;
    if (dir == 0) {
        int t0 = outLo - WARMUP; if (t0 < 0) t0 = 0;
        t = t0; nsteps = outLo + S_CHUNK - t0; tstep = 1;
    } else {
        int t1 = outLo + S_CHUNK - 1 + WARMUP; if (t1 > N_NODES - 1) t1 = N_NODES - 1;
        t = t1; nsteps = t1 - outLo + 1; tstep = -1;
    }
    float g = gpre[(size_t)t * 256 + tid];
    for (int s = 0; s < nsteps; s++) {
        int tcur = t;
        t += tstep;
        int tn = t < 0 ? 0 : (t > N_NODES - 1 ? N_NODES - 1 : t);
        float gnext = gpre[(size_t)tn * 256 + tid];  // prefetch next step
        float a0 = g, a1 = 0.f, a2 = 0.f, a3 = 0.f;
        #pragma unroll
        for (int k = 0; k < 64; k += 4) {
            a0 += wreg[k + 0] * bcastlane(h, k + 0);
            a1 += wreg[k + 1] * bcastlane(h, k + 1);
            a2 += wreg[k + 2] * bcastlane(h, k + 2);
            a3 += wreg[k + 3] * bcastlane(h, k + 3);
        }
        float pre = (a0 + a1) + (a2 + a3);
        float a = (wv == 2) ? tanh_f(pre) : sigm_f(pre);
        int buf = s & 1;
        act[buf][tid] = a;
        __syncthreads();
        float ia = act[buf][lane];
        float fa = act[buf][64 + lane];
        float ga = act[buf][128 + lane];
        float oa = act[buf][192 + lane];
        c = fa * c + ia * ga;           // replicated identically across all 4 waves
        h = oa * tanh_f(c);
        if (wv == 0) {
            unsigned rel = (unsigned)(tcur - outLo);
            if (rel < S_CHUNK) hout[(size_t)tcur * 64 + lane] = h;
        }
        g = gnext;
    }
}

// ---------------- output layer ----------------

__global__ __launch_bounds__(256) void k_final(const float* __restrict__ hf,
        const float* __restrict__ hb, const float* __restrict__ Wl,
        const float* __restrict__ bl, float* __restrict__ out) {
    int i = blockIdx.x * 256 + threadIdx.x;
    const float4* hfp = (const float4*)(hf + (size_t)i * 64);
    const float4* hbp = (const float4*)(hb + (size_t)i * 64);
    float acc = bl[0];
    #pragma unroll
    for (int k = 0; k < 16; k++) {
        float4 h4 = hfp[k];
        float4 w4 = *(const float4*)&Wl[k * 4];
        acc += h4.x * w4.x + h4.y * w4.y + h4.z * w4.z + h4.w * w4.w;
    }
    #pragma unroll
    for (int k = 0; k < 16; k++) {
        float4 h4 = hbp[k];
        float4 w4 = *(const float4*)&Wl[64 + k * 4];
        acc += h4.x * w4.x + h4.y * w4.y + h4.z * w4.z + h4.w * w4.w;
    }
    out[i] = 1.0f / (1.0f + __expf(-acc));
}

extern "C" void kernel_launch(void* const* d_in, const int* in_sizes, int n_in,
                              void* d_out, int out_size, void* d_ws, size_t ws_size,
                              hipStream_t stream) {
    const float* x     = (const float*)d_in[0];
    const int*   ei    = (const int*)d_in[1];
    const float* ew    = (const float*)d_in[2];
    const float* W1    = (const float*)d_in[3];
    const float* b1    = (const float*)d_in[4];
    const float* W2    = (const float*)d_in[5];
    const float* b2    = (const float*)d_in[6];
    const float* Wih_f = (const float*)d_in[7];
    const float* Whh_f = (const float*)d_in[8];
    const float* bih_f = (const float*)d_in[9];
    const float* bhh_f = (const float*)d_in[10];
    const float* Wih_b = (const float*)d_in[11];
    const float* Whh_b = (const float*)d_in[12];
    const float* bih_b = (const float*)d_in[13];
    const float* bhh_b = (const float*)d_in[14];
    const float* Wl    = (const float*)d_in[15];
    const float* bl    = (const float*)d_in[16];
    const int* erow = ei;            // edge_index[0] = source
    const int* ecol = ei + N_EDGES;  // edge_index[1] = target

    float* ws = (float*)d_ws;
    size_t o = 0;
    auto alloc = [&](size_t n) { float* p = ws + o; o += n; return p; };
    float* xl    = alloc((size_t)N_NODES * 128);   // GEMM outputs (pre-aggregation)
    float* hbuf  = alloc((size_t)N_NODES * 128);   // conv outputs
    float* gpf   = alloc((size_t)N_NODES * 256);   // Wih_f@h + biases
    float* gpb   = alloc((size_t)N_NODES * 256);
    float* hf    = alloc((size_t)N_NODES * 64);
    float* hb    = alloc((size_t)N_NODES * 64);
    float* deg   = alloc(N_NODES);                 // deg,cnt,cur contiguous: one memset
    int*   cnt   = (int*)alloc(N_NODES);
    int*   cur   = (int*)alloc(N_NODES);
    float* dis   = alloc(N_NODES);
    int*   off   = (int*)alloc(N_NODES + 4);
    int*   srow  = (int*)alloc(N_EDGES);
    float* snorm = alloc(N_EDGES);
    (void)o; (void)ws_size; (void)in_sizes; (void)n_in; (void)out_size;

    hipMemsetAsync(deg, 0, (size_t)N_NODES * 4 * 3, stream);
    k_hist<<<N_EDGES / 256, 256, 0, stream>>>(ecol, ew, cnt, deg);
    k_scan<<<1, 1024, 0, stream>>>(cnt, deg, off, dis);
    k_scatter<<<N_EDGES / 256, 256, 0, stream>>>(erow, ecol, ew, off, cur, dis, srow, snorm);
    k_gemm_rows<768, 128><<<N_NODES / 4, 256, 0, stream>>>(x, W1, nullptr, nullptr, xl);
    k_conv<<<N_NODES, 128, 0, stream>>>(xl, srow, snorm, off, b1, hbuf);
    k_gemm_rows<128, 128><<<N_NODES / 4, 256, 0, stream>>>(hbuf, W2, nullptr, nullptr, xl);
    k_conv<<<N_NODES, 128, 0, stream>>>(xl, srow, snorm, off, b2, hbuf);
    k_gemm_rows<128, 256><<<N_NODES / 4, 256, 0, stream>>>(hbuf, Wih_f, bih_f, bhh_f, gpf);
    k_gemm_rows<128, 256><<<N_NODES / 4, 256, 0, stream>>>(hbuf, Wih_b, bih_b, bhh_b, gpb);
    k_lstm<<<2 * NCHUNK, 256, 0, stream>>>(gpf, gpb, Whh_f, Whh_b, hf, hb);
    k_final<<<N_NODES / 256, 256, 0, stream>>>(hf, hb, Wl, bl, (float*)d_out);
}

// Round 2
// 761.624 us; speedup vs baseline: 2.6703x; 2.6703x over previous
//
#include <hip/hip_runtime.h>

#define N_NODES 16384
#define N_EDGES 1048576
#define D_IN 768
#define D_H 128
#define H_LSTM 64
#define S_CHUNK 128
#define NCHUNK (N_NODES / S_CHUNK)   // 128
#define WARMUP 256

static_assert(NCHUNK == 128, "lstm kernel assumes 128 chunks");

__device__ __forceinline__ float sigm_f(float x) { return 1.0f / (1.0f + __expf(-x)); }
__device__ __forceinline__ float tanh_f(float x) {
    float e = __expf(2.0f * x);
    return 1.0f - 2.0f / (e + 1.0f);
}
__device__ __forceinline__ float bcastlane(float v, int l) {
    return __int_as_float(__builtin_amdgcn_readlane(__float_as_int(v), l));
}

// ---------------- graph preprocessing: counting sort of edges by target ----------------

__global__ __launch_bounds__(256) void k_hist(const int* __restrict__ col,
        const float* __restrict__ w, int* __restrict__ cnt, float* __restrict__ deg) {
    int e = blockIdx.x * 256 + threadIdx.x;
    int c = col[e];
    atomicAdd(&cnt[c], 1);
    atomicAdd(&deg[c], w[e]);
}

__global__ __launch_bounds__(1024) void k_scan(const int* __restrict__ cnt,
        const float* __restrict__ deg, int* __restrict__ off, float* __restrict__ dis) {
    __shared__ int part[1024];
    int t = threadIdx.x;
    int base = t * 16;
    int loc[16];
    int sum = 0;
    #pragma unroll
    for (int i = 0; i < 16; i++) { loc[i] = sum; sum += cnt[base + i]; }
    part[t] = sum;
    __syncthreads();
    for (int ofs = 1; ofs < 1024; ofs <<= 1) {
        int add = (t >= ofs) ? part[t - ofs] : 0;
        __syncthreads();
        part[t] += add;
        __syncthreads();
    }
    int excl = part[t] - sum;
    #pragma unroll
    for (int i = 0; i < 16; i++) off[base + i] = excl + loc[i];
    if (t == 1023) off[N_NODES] = part[1023];
    #pragma unroll
    for (int i = 0; i < 16; i++) {
        float d = deg[base + i];
        dis[base + i] = (d > 0.0f) ? rsqrtf(d) : 0.0f;
    }
}

__global__ __launch_bounds__(256) void k_scatter(const int* __restrict__ row,
        const int* __restrict__ col, const float* __restrict__ w,
        const int* __restrict__ off, int* __restrict__ cur,
        const float* __restrict__ dis, int* __restrict__ srow, float* __restrict__ snorm) {
    int e = blockIdx.x * 256 + threadIdx.x;
    int c = col[e], r = row[e];
    int p = off[c] + atomicAdd(&cur[c], 1);
    srow[p] = r;
    snorm[p] = dis[r] * w[e] * dis[c];
}

// ---------------- tiled GEMM: C[M][N] = A[M][K] @ W[N][K]^T (+ b1 + b2) ----------------
// 64x128 output tile per 256-thread block, BK=32. A and W staged transposed in LDS
// ([k][m] / [k][n], padded strides 68/132: 16B-aligned rows, spread write banks).
// All global loads are float4 along K (coalesced). Micro-tile 8x4 per thread.

template <int K, int N>
__global__ __launch_bounds__(256) void k_gemm_tiled(const float* __restrict__ A,
        const float* __restrict__ W, const float* __restrict__ b1,
        const float* __restrict__ b2, float* __restrict__ C) {
    constexpr int BM = 64, BN = 128, BK = 32;
    __shared__ float sA[BK][68];    // [k][m], 272B rows (16B-aligned)
    __shared__ float sW[BK][132];   // [k][n], 528B rows (16B-aligned)
    int tid = threadIdx.x;
    int m0 = blockIdx.x * BM;
    int n0 = blockIdx.y * BN;
    int tr = tid >> 5;              // 0..7  -> rows tr*8 .. tr*8+7
    int tc = tid & 31;              // 0..31 -> cols tc*4 .. tc*4+3
    int lm = tid >> 3;              // 0..31 (global-load row within pass)
    int lk = (tid & 7) * 4;         // float4 position along k
    float acc[8][4] = {};
    for (int k0 = 0; k0 < K; k0 += BK) {
        #pragma unroll
        for (int p = 0; p < 2; p++) {
            int m = lm + 32 * p;
            float4 a4 = *(const float4*)&A[(size_t)(m0 + m) * K + k0 + lk];
            sA[lk + 0][m] = a4.x; sA[lk + 1][m] = a4.y;
            sA[lk + 2][m] = a4.z; sA[lk + 3][m] = a4.w;
        }
        #pragma unroll
        for (int p = 0; p < 4; p++) {
            int n = lm + 32 * p;
            float4 w4 = *(const float4*)&W[(size_t)(n0 + n) * K + k0 + lk];
            sW[lk + 0][n] = w4.x; sW[lk + 1][n] = w4.y;
            sW[lk + 2][n] = w4.z; sW[lk + 3][n] = w4.w;
        }
        __syncthreads();
        #pragma unroll
        for (int kk = 0; kk < BK; kk++) {
            float4 a0 = *(const float4*)&sA[kk][tr * 8];
            float4 a1 = *(const float4*)&sA[kk][tr * 8 + 4];
            float4 b4 = *(const float4*)&sW[kk][tc * 4];
            float av[8] = {a0.x, a0.y, a0.z, a0.w, a1.x, a1.y, a1.z, a1.w};
            float bv[4] = {b4.x, b4.y, b4.z, b4.w};
            #pragma unroll
            for (int i = 0; i < 8; i++)
                #pragma unroll
                for (int j = 0; j < 4; j++)
                    acc[i][j] += av[i] * bv[j];
        }
        __syncthreads();
    }
    int cb = n0 + tc * 4;
    float badd[4] = {0.f, 0.f, 0.f, 0.f};
    #pragma unroll
    for (int j = 0; j < 4; j++) {
        if (b1) badd[j] += b1[cb + j];
        if (b2) badd[j] += b2[cb + j];
    }
    #pragma unroll
    for (int i = 0; i < 8; i++) {
        size_t r = (size_t)(m0 + tr * 8 + i);
        float4 v = {acc[i][0] + badd[0], acc[i][1] + badd[1],
                    acc[i][2] + badd[2], acc[i][3] + badd[3]};
        *(float4*)&C[r * N + cb] = v;
    }
}

// ---------------- GCN aggregation: one block per target node ----------------

__global__ __launch_bounds__(128) void k_conv(const float* __restrict__ xl,
        const int* __restrict__ srow, const float* __restrict__ snorm,
        const int* __restrict__ off, const float* __restrict__ bias,
        float* __restrict__ out) {
    int n = blockIdx.x, d = threadIdx.x;
    int p0 = off[n], p1 = off[n + 1];
    float acc = 0.0f;
    for (int p = p0; p < p1; p++) {
        int r = srow[p];
        float nm = snorm[p];
        acc += nm * xl[(size_t)r * 128 + d];
    }
    out[(size_t)n * 128 + d] = fmaxf(acc + bias[d], 0.0f);
}

// ---------------- chunked bidirectional LSTM ----------------
// grid = 256 blocks: blocks 0..127 forward chunks, 128..255 backward chunks.
// 4 waves per block: wave w computes gate-type w (i,f,g,o) for all 64 units.
// Whh row per thread lives in 64 VGPRs; h broadcast via v_readlane; one barrier/step.

__global__ __launch_bounds__(256) void k_lstm(const float* __restrict__ gpf,
        const float* __restrict__ gpb, const float* __restrict__ Whh_f,
        const float* __restrict__ Whh_b, float* __restrict__ hf, float* __restrict__ hb) {
    int b = blockIdx.x;
    int dir = b >> 7;
    int ch = b & 127;
    const float* gpre = dir ? gpb : gpf;
    const float* Whh = dir ? Whh_b : Whh_f;
    float* hout = dir ? hb : hf;
    int tid = threadIdx.x, lane = tid & 63, wv = tid >> 6;
    float wreg[64];
    #pragma unroll
    for (int k = 0; k < 64; k++) wreg[k] = Whh[tid * 64 + k];
    __shared__ float act[2][256];
    float c = 0.0f, h = 0.0f;
    int outLo = ch * S_CHUNK;
    int t, nsteps, tstep;
    if (dir == 0) {
        int t0 = outLo - WARMUP; if (t0 < 0) t0 = 0;
        t = t0; nsteps = outLo + S_CHUNK - t0; tstep = 1;
    } else {
        int t1 = outLo + S_CHUNK - 1 + WARMUP; if (t1 > N_NODES - 1) t1 = N_NODES - 1;
        t = t1; nsteps = t1 - outLo + 1; tstep = -1;
    }
    float g = gpre[(size_t)t * 256 + tid];
    for (int s = 0; s < nsteps; s++) {
        int tcur = t;
        t += tstep;
        int tn = t < 0 ? 0 : (t > N_NODES - 1 ? N_NODES - 1 : t);
        float gnext = gpre[(size_t)tn * 256 + tid];  // prefetch next step
        float a0 = g, a1 = 0.f, a2 = 0.f, a3 = 0.f;
        #pragma unroll
        for (int k = 0; k < 64; k += 4) {
            a0 += wreg[k + 0] * bcastlane(h, k + 0);
            a1 += wreg[k + 1] * bcastlane(h, k + 1);
            a2 += wreg[k + 2] * bcastlane(h, k + 2);
            a3 += wreg[k + 3] * bcastlane(h, k + 3);
        }
        float pre = (a0 + a1) + (a2 + a3);
        float a = (wv == 2) ? tanh_f(pre) : sigm_f(pre);
        int buf = s & 1;
        act[buf][tid] = a;
        __syncthreads();
        float ia = act[buf][lane];
        float fa = act[buf][64 + lane];
        float ga = act[buf][128 + lane];
        float oa = act[buf][192 + lane];
        c = fa * c + ia * ga;           // replicated identically across all 4 waves
        h = oa * tanh_f(c);
        if (wv == 0) {
            unsigned rel = (unsigned)(tcur - outLo);
            if (rel < S_CHUNK) hout[(size_t)tcur * 64 + lane] = h;
        }
        g = gnext;
    }
}

// ---------------- output layer ----------------

__global__ __launch_bounds__(256) void k_final(const float* __restrict__ hf,
        const float* __restrict__ hb, const float* __restrict__ Wl,
        const float* __restrict__ bl, float* __restrict__ out) {
    int i = blockIdx.x * 256 + threadIdx.x;
    const float4* hfp = (const float4*)(hf + (size_t)i * 64);
    const float4* hbp = (const float4*)(hb + (size_t)i * 64);
    float acc = bl[0];
    #pragma unroll
    for (int k = 0; k < 16; k++) {
        float4 h4 = hfp[k];
        float4 w4 = *(const float4*)&Wl[k * 4];
        acc += h4.x * w4.x + h4.y * w4.y + h4.z * w4.z + h4.w * w4.w;
    }
    #pragma unroll
    for (int k = 0; k < 16; k++) {
        float4 h4 = hbp[k];
        float4 w4 = *(const float4*)&Wl[64 + k * 4];
        acc += h4.x * w4.x + h4.y * w4.y + h4.z * w4.z + h4.w * w4.w;
    }
    out[i] = 1.0f / (1.0f + __expf(-acc));
}

extern "C" void kernel_launch(void* const* d_in, const int* in_sizes, int n_in,
                              void* d_out, int out_size, void* d_ws, size_t ws_size,
                              hipStream_t stream) {
    const float* x     = (const float*)d_in[0];
    const int*   ei    = (const int*)d_in[1];
    const float* ew    = (const float*)d_in[2];
    const float* W1    = (const float*)d_in[3];
    const float* b1    = (const float*)d_in[4];
    const float* W2    = (const float*)d_in[5];
    const float* b2    = (const float*)d_in[6];
    const float* Wih_f = (const float*)d_in[7];
    const float* Whh_f = (const float*)d_in[8];
    const float* bih_f = (const float*)d_in[9];
    const float* bhh_f = (const float*)d_in[10];
    const float* Wih_b = (const float*)d_in[11];
    const float* Whh_b = (const float*)d_in[12];
    const float* bih_b = (const float*)d_in[13];
    const float* bhh_b = (const float*)d_in[14];
    const float* Wl    = (const float*)d_in[15];
    const float* bl    = (const float*)d_in[16];
    const int* erow = ei;            // edge_index[0] = source
    const int* ecol = ei + N_EDGES;  // edge_index[1] = target

    float* ws = (float*)d_ws;
    size_t o = 0;
    auto alloc = [&](size_t n) { float* p = ws + o; o += n; return p; };
    float* xl    = alloc((size_t)N_NODES * 128);   // GEMM outputs (pre-aggregation)
    float* hbuf  = alloc((size_t)N_NODES * 128);   // conv outputs
    float* gpf   = alloc((size_t)N_NODES * 256);   // Wih_f@h + biases
    float* gpb   = alloc((size_t)N_NODES * 256);
    float* hf    = alloc((size_t)N_NODES * 64);
    float* hb    = alloc((size_t)N_NODES * 64);
    float* deg   = alloc(N_NODES);                 // deg,cnt,cur contiguous: one memset
    int*   cnt   = (int*)alloc(N_NODES);
    int*   cur   = (int*)alloc(N_NODES);
    float* dis   = alloc(N_NODES);
    int*   off   = (int*)alloc(N_NODES + 4);
    int*   srow  = (int*)alloc(N_EDGES);
    float* snorm = alloc(N_EDGES);
    (void)o; (void)ws_size; (void)in_sizes; (void)n_in; (void)out_size;

    hipMemsetAsync(deg, 0, (size_t)N_NODES * 4 * 3, stream);
    k_hist<<<N_EDGES / 256, 256, 0, stream>>>(ecol, ew, cnt, deg);
    k_scan<<<1, 1024, 0, stream>>>(cnt, deg, off, dis);
    k_scatter<<<N_EDGES / 256, 256, 0, stream>>>(erow, ecol, ew, off, cur, dis, srow, snorm);
    k_gemm_tiled<768, 128><<<dim3(N_NODES / 64, 1), 256, 0, stream>>>(x, W1, nullptr, nullptr, xl);
    k_conv<<<N_NODES, 128, 0, stream>>>(xl, srow, snorm, off, b1, hbuf);
    k_gemm_tiled<128, 128><<<dim3(N_NODES / 64, 1), 256, 0, stream>>>(hbuf, W2, nullptr, nullptr, xl);
    k_conv<<<N_NODES, 128, 0, stream>>>(xl, srow, snorm, off, b2, hbuf);
    k_gemm_tiled<128, 256><<<dim3(N_NODES / 64, 2), 256, 0, stream>>>(hbuf, Wih_f, bih_f, bhh_f, gpf);
    k_gemm_tiled<128, 256><<<dim3(N_NODES / 64, 2), 256, 0, stream>>>(hbuf, Wih_b, bih_b, bhh_b, gpb);
    k_lstm<<<2 * NCHUNK, 256, 0, stream>>>(gpf, gpb, Whh_f, Whh_b, hf, hb);
    k_final<<<N_NODES / 256, 256, 0, stream>>>(hf, hb, Wl, bl, (float*)d_out);
}

// Round 3
// 669.610 us; speedup vs baseline: 3.0372x; 1.1374x over previous
//
#include <hip/hip_runtime.h>

#define N_NODES 16384
#define N_EDGES 1048576
#define D_IN 768
#define D_H 128
#define H_LSTM 64
#define S_CHUNK 32
#define NCHUNK (N_NODES / S_CHUNK)   // 512 chunks per direction
#define WARMUP 192

static_assert(NCHUNK == 512, "lstm kernel assumes 512 chunks/dir");

__device__ __forceinline__ float sigm_f(float x) { return 1.0f / (1.0f + __expf(-x)); }
__device__ __forceinline__ float tanh_f(float x) {
    float e = __expf(2.0f * x);
    return 1.0f - 2.0f / (e + 1.0f);
}
__device__ __forceinline__ float bcastlane(float v, int l) {
    return __int_as_float(__builtin_amdgcn_readlane(__float_as_int(v), l));
}

// ---------------- graph preprocessing: counting sort of edges by target ----------------

__global__ __launch_bounds__(256) void k_hist(const int* __restrict__ col,
        const float* __restrict__ w, int* __restrict__ cnt, float* __restrict__ deg) {
    int e = blockIdx.x * 256 + threadIdx.x;
    int c = col[e];
    atomicAdd(&cnt[c], 1);
    atomicAdd(&deg[c], w[e]);
}

__global__ __launch_bounds__(1024) void k_scan(const int* __restrict__ cnt,
        const float* __restrict__ deg, int* __restrict__ off, float* __restrict__ dis) {
    __shared__ int part[1024];
    int t = threadIdx.x;
    int base = t * 16;
    int loc[16];
    int sum = 0;
    #pragma unroll
    for (int i = 0; i < 16; i++) { loc[i] = sum; sum += cnt[base + i]; }
    part[t] = sum;
    __syncthreads();
    for (int ofs = 1; ofs < 1024; ofs <<= 1) {
        int add = (t >= ofs) ? part[t - ofs] : 0;
        __syncthreads();
        part[t] += add;
        __syncthreads();
    }
    int excl = part[t] - sum;
    #pragma unroll
    for (int i = 0; i < 16; i++) off[base + i] = excl + loc[i];
    if (t == 1023) off[N_NODES] = part[1023];
    #pragma unroll
    for (int i = 0; i < 16; i++) {
        float d = deg[base + i];
        dis[base + i] = (d > 0.0f) ? rsqrtf(d) : 0.0f;
    }
}

__global__ __launch_bounds__(256) void k_scatter(const int* __restrict__ row,
        const int* __restrict__ col, const float* __restrict__ w,
        const int* __restrict__ off, int* __restrict__ cur,
        const float* __restrict__ dis, int* __restrict__ srow, float* __restrict__ snorm) {
    int e = blockIdx.x * 256 + threadIdx.x;
    int c = col[e], r = row[e];
    int p = off[c] + atomicAdd(&cur[c], 1);
    srow[p] = r;
    snorm[p] = dis[r] * w[e] * dis[c];
}

// ---------------- tiled GEMM: C[M][N] = A[M][K] @ W[N][K]^T (+ b1 + b2) ----------------

template <int K, int N>
__global__ __launch_bounds__(256) void k_gemm_tiled(const float* __restrict__ A,
        const float* __restrict__ W, const float* __restrict__ b1,
        const float* __restrict__ b2, float* __restrict__ C) {
    constexpr int BM = 64, BN = 128, BK = 32;
    __shared__ float sA[BK][68];    // [k][m], 272B rows (16B-aligned)
    __shared__ float sW[BK][132];   // [k][n], 528B rows (16B-aligned)
    int tid = threadIdx.x;
    int m0 = blockIdx.x * BM;
    int n0 = blockIdx.y * BN;
    int tr = tid >> 5;              // 0..7  -> rows tr*8 .. tr*8+7
    int tc = tid & 31;              // 0..31 -> cols tc*4 .. tc*4+3
    int lm = tid >> 3;              // 0..31 (global-load row within pass)
    int lk = (tid & 7) * 4;         // float4 position along k
    float acc[8][4] = {};
    for (int k0 = 0; k0 < K; k0 += BK) {
        #pragma unroll
        for (int p = 0; p < 2; p++) {
            int m = lm + 32 * p;
            float4 a4 = *(const float4*)&A[(size_t)(m0 + m) * K + k0 + lk];
            sA[lk + 0][m] = a4.x; sA[lk + 1][m] = a4.y;
            sA[lk + 2][m] = a4.z; sA[lk + 3][m] = a4.w;
        }
        #pragma unroll
        for (int p = 0; p < 4; p++) {
            int n = lm + 32 * p;
            float4 w4 = *(const float4*)&W[(size_t)(n0 + n) * K + k0 + lk];
            sW[lk + 0][n] = w4.x; sW[lk + 1][n] = w4.y;
            sW[lk + 2][n] = w4.z; sW[lk + 3][n] = w4.w;
        }
        __syncthreads();
        #pragma unroll
        for (int kk = 0; kk < BK; kk++) {
            float4 a0 = *(const float4*)&sA[kk][tr * 8];
            float4 a1 = *(const float4*)&sA[kk][tr * 8 + 4];
            float4 b4 = *(const float4*)&sW[kk][tc * 4];
            float av[8] = {a0.x, a0.y, a0.z, a0.w, a1.x, a1.y, a1.z, a1.w};
            float bv[4] = {b4.x, b4.y, b4.z, b4.w};
            #pragma unroll
            for (int i = 0; i < 8; i++)
                #pragma unroll
                for (int j = 0; j < 4; j++)
                    acc[i][j] += av[i] * bv[j];
        }
        __syncthreads();
    }
    int cb = n0 + tc * 4;
    float badd[4] = {0.f, 0.f, 0.f, 0.f};
    #pragma unroll
    for (int j = 0; j < 4; j++) {
        if (b1) badd[j] += b1[cb + j];
        if (b2) badd[j] += b2[cb + j];
    }
    #pragma unroll
    for (int i = 0; i < 8; i++) {
        size_t r = (size_t)(m0 + tr * 8 + i);
        float4 v = {acc[i][0] + badd[0], acc[i][1] + badd[1],
                    acc[i][2] + badd[2], acc[i][3] + badd[3]};
        *(float4*)&C[r * N + cb] = v;
    }
}

// ---------------- GCN aggregation: one block per target node ----------------

__global__ __launch_bounds__(128) void k_conv(const float* __restrict__ xl,
        const int* __restrict__ srow, const float* __restrict__ snorm,
        const int* __restrict__ off, const float* __restrict__ bias,
        float* __restrict__ out) {
    int n = blockIdx.x, d = threadIdx.x;
    int p0 = off[n], p1 = off[n + 1];
    float acc = 0.0f;
    for (int p = p0; p < p1; p++) {
        int r = srow[p];
        float nm = snorm[p];
        acc += nm * xl[(size_t)r * 128 + d];
    }
    out[(size_t)n * 128 + d] = fmaxf(acc + bias[d], 0.0f);
}

// ---------------- chunked bidirectional LSTM: one wave per chunk ----------------
// 1024 blocks x 64 threads. Blocks 0..511 forward, 512..1023 backward.
// Lane u owns unit u: all 4 Whh rows (i,f,g,o) in 256 VGPRs. h broadcast via
// v_readlane (shared across the 4 gates). No barriers, no LDS. Gate
// pre-activations prefetched 4 steps ahead into 4 named float4 registers
// (static indexing; all nsteps are divisible by 4 by construction).

#define LSTM_LOADG(G)                                                           \
    {                                                                           \
        int tt = tload < 0 ? 0 : (tload > N_NODES - 1 ? N_NODES - 1 : tload);   \
        const float* p = gpre + (size_t)tt * 256 + u;                           \
        G.x = p[0]; G.y = p[64]; G.z = p[128]; G.w = p[192];                    \
        tload += tstep;                                                         \
    }

#define LSTM_STEP(G)                                                            \
    {                                                                           \
        float si = G.x, sf = G.y, sg = G.z, so = G.w;                           \
        float si2 = 0.f, sf2 = 0.f, sg2 = 0.f, so2 = 0.f;                       \
        _Pragma("unroll")                                                       \
        for (int k = 0; k < 64; k += 2) {                                       \
            float h0 = bcastlane(h, k);                                         \
            float h1 = bcastlane(h, k + 1);                                     \
            si  += wi[k] * h0;     sf  += wf[k] * h0;                           \
            sg  += wg[k] * h0;     so  += wo[k] * h0;                           \
            si2 += wi[k + 1] * h1; sf2 += wf[k + 1] * h1;                       \
            sg2 += wg[k + 1] * h1; so2 += wo[k + 1] * h1;                       \
        }                                                                       \
        float iv = sigm_f(si + si2);                                            \
        float fv = sigm_f(sf + sf2);                                            \
        float gv = tanh_f(sg + sg2);                                            \
        float ov = sigm_f(so + so2);                                            \
        c = fv * c + iv * gv;                                                   \
        h = ov * tanh_f(c);                                                     \
        unsigned rel = (unsigned)(tcur - outLo);                                \
        if (rel < S_CHUNK) hout[(size_t)tcur * 64 + u] = h;                     \
        tcur += tstep;                                                          \
    }

__global__ __launch_bounds__(64, 1) void k_lstm(const float* __restrict__ gpf,
        const float* __restrict__ gpb, const float* __restrict__ Whh_f,
        const float* __restrict__ Whh_b, float* __restrict__ hf, float* __restrict__ hb) {
    int b = blockIdx.x;
    int dir = b >> 9;
    int ch = b & (NCHUNK - 1);
    const float* gpre = dir ? gpb : gpf;
    const float* Whh = dir ? Whh_b : Whh_f;
    float* hout = dir ? hb : hf;
    int u = threadIdx.x;            // unit 0..63
    float wi[64], wf[64], wg[64], wo[64];
    {
        const float4* Wr = (const float4*)Whh;   // [256][16] float4
        #pragma unroll
        for (int k4 = 0; k4 < 16; k4++) {
            float4 a = Wr[(size_t)(0 * 64 + u) * 16 + k4];
            wi[4*k4+0] = a.x; wi[4*k4+1] = a.y; wi[4*k4+2] = a.z; wi[4*k4+3] = a.w;
            float4 bq = Wr[(size_t)(1 * 64 + u) * 16 + k4];
            wf[4*k4+0] = bq.x; wf[4*k4+1] = bq.y; wf[4*k4+2] = bq.z; wf[4*k4+3] = bq.w;
            float4 cq = Wr[(size_t)(2 * 64 + u) * 16 + k4];
            wg[4*k4+0] = cq.x; wg[4*k4+1] = cq.y; wg[4*k4+2] = cq.z; wg[4*k4+3] = cq.w;
            float4 dq = Wr[(size_t)(3 * 64 + u) * 16 + k4];
            wo[4*k4+0] = dq.x; wo[4*k4+1] = dq.y; wo[4*k4+2] = dq.z; wo[4*k4+3] = dq.w;
        }
    }
    int outLo = ch * S_CHUNK;
    int tstart, nsteps, tstep;
    if (dir == 0) {
        int t0 = outLo - WARMUP; if (t0 < 0) t0 = 0;
        tstart = t0; nsteps = outLo + S_CHUNK - t0; tstep = 1;
    } else {
        int t1 = outLo + S_CHUNK - 1 + WARMUP; if (t1 > N_NODES - 1) t1 = N_NODES - 1;
        tstart = t1; nsteps = t1 - outLo + 1; tstep = -1;
    }
    int tload = tstart, tcur = tstart;
    float4 G0, G1, G2, G3;
    LSTM_LOADG(G0); LSTM_LOADG(G1); LSTM_LOADG(G2); LSTM_LOADG(G3);
    float c = 0.0f, h = 0.0f;
    for (int s = 0; s < nsteps; s += 4) {
        LSTM_STEP(G0); LSTM_LOADG(G0);
        LSTM_STEP(G1); LSTM_LOADG(G1);
        LSTM_STEP(G2); LSTM_LOADG(G2);
        LSTM_STEP(G3); LSTM_LOADG(G3);
    }
}

// ---------------- output layer ----------------

__global__ __launch_bounds__(256) void k_final(const float* __restrict__ hf,
        const float* __restrict__ hb, const float* __restrict__ Wl,
        const float* __restrict__ bl, float* __restrict__ out) {
    int i = blockIdx.x * 256 + threadIdx.x;
    const float4* hfp = (const float4*)(hf + (size_t)i * 64);
    const float4* hbp = (const float4*)(hb + (size_t)i * 64);
    float acc = bl[0];
    #pragma unroll
    for (int k = 0; k < 16; k++) {
        float4 h4 = hfp[k];
        float4 w4 = *(const float4*)&Wl[k * 4];
        acc += h4.x * w4.x + h4.y * w4.y + h4.z * w4.z + h4.w * w4.w;
    }
    #pragma unroll
    for (int k = 0; k < 16; k++) {
        float4 h4 = hbp[k];
        float4 w4 = *(const float4*)&Wl[64 + k * 4];
        acc += h4.x * w4.x + h4.y * w4.y + h4.z * w4.z + h4.w * w4.w;
    }
    out[i] = 1.0f / (1.0f + __expf(-acc));
}

extern "C" void kernel_launch(void* const* d_in, const int* in_sizes, int n_in,
                              void* d_out, int out_size, void* d_ws, size_t ws_size,
                              hipStream_t stream) {
    const float* x     = (const float*)d_in[0];
    const int*   ei    = (const int*)d_in[1];
    const float* ew    = (const float*)d_in[2];
    const float* W1    = (const float*)d_in[3];
    const float* b1    = (const float*)d_in[4];
    const float* W2    = (const float*)d_in[5];
    const float* b2    = (const float*)d_in[6];
    const float* Wih_f = (const float*)d_in[7];
    const float* Whh_f = (const float*)d_in[8];
    const float* bih_f = (const float*)d_in[9];
    const float* bhh_f = (const float*)d_in[10];
    const float* Wih_b = (const float*)d_in[11];
    const float* Whh_b = (const float*)d_in[12];
    const float* bih_b = (const float*)d_in[13];
    const float* bhh_b = (const float*)d_in[14];
    const float* Wl    = (const float*)d_in[15];
    const float* bl    = (const float*)d_in[16];
    const int* erow = ei;            // edge_index[0] = source
    const int* ecol = ei + N_EDGES;  // edge_index[1] = target

    float* ws = (float*)d_ws;
    size_t o = 0;
    auto alloc = [&](size_t n) { float* p = ws + o; o += n; return p; };
    float* xl    = alloc((size_t)N_NODES * 128);   // GEMM outputs (pre-aggregation)
    float* hbuf  = alloc((size_t)N_NODES * 128);   // conv outputs
    float* gpf   = alloc((size_t)N_NODES * 256);   // Wih_f@h + biases
    float* gpb   = alloc((size_t)N_NODES * 256);
    float* hf    = alloc((size_t)N_NODES * 64);
    float* hb    = alloc((size_t)N_NODES * 64);
    float* deg   = alloc(N_NODES);                 // deg,cnt,cur contiguous: one memset
    int*   cnt   = (int*)alloc(N_NODES);
    int*   cur   = (int*)alloc(N_NODES);
    float* dis   = alloc(N_NODES);
    int*   off   = (int*)alloc(N_NODES + 4);
    int*   srow  = (int*)alloc(N_EDGES);
    float* snorm = alloc(N_EDGES);
    (void)o; (void)ws_size; (void)in_sizes; (void)n_in; (void)out_size;

    hipMemsetAsync(deg, 0, (size_t)N_NODES * 4 * 3, stream);
    k_hist<<<N_EDGES / 256, 256, 0, stream>>>(ecol, ew, cnt, deg);
    k_scan<<<1, 1024, 0, stream>>>(cnt, deg, off, dis);
    k_scatter<<<N_EDGES / 256, 256, 0, stream>>>(erow, ecol, ew, off, cur, dis, srow, snorm);
    k_gemm_tiled<768, 128><<<dim3(N_NODES / 64, 1), 256, 0, stream>>>(x, W1, nullptr, nullptr, xl);
    k_conv<<<N_NODES, 128, 0, stream>>>(xl, srow, snorm, off, b1, hbuf);
    k_gemm_tiled<128, 128><<<dim3(N_NODES / 64, 1), 256, 0, stream>>>(hbuf, W2, nullptr, nullptr, xl);
    k_conv<<<N_NODES, 128, 0, stream>>>(xl, srow, snorm, off, b2, hbuf);
    k_gemm_tiled<128, 256><<<dim3(N_NODES / 64, 2), 256, 0, stream>>>(hbuf, Wih_f, bih_f, bhh_f, gpf);
    k_gemm_tiled<128, 256><<<dim3(N_NODES / 64, 2), 256, 0, stream>>>(hbuf, Wih_b, bih_b, bhh_b, gpb);
    k_lstm<<<2 * NCHUNK, 64, 0, stream>>>(gpf, gpb, Whh_f, Whh_b, hf, hb);
    k_final<<<N_NODES / 256, 256, 0, stream>>>(hf, hb, Wl, bl, (float*)d_out);
}

// Round 4
// 545.010 us; speedup vs baseline: 3.7315x; 1.2286x over previous
//
#include <hip/hip_runtime.h>

#define N_NODES 16384
#define N_EDGES 1048576
#define D_IN 768
#define D_H 128
#define H_LSTM 64
#define S_CHUNK 32
#define NCHUNK (N_NODES / S_CHUNK)   // 512 chunks per direction
#define WARMUP 96

static_assert(NCHUNK == 512, "lstm kernel assumes 512 chunks/dir");

__device__ __forceinline__ float sigm_f(float x) { return 1.0f / (1.0f + __expf(-x)); }
__device__ __forceinline__ float tanh_f(float x) {
    float e = __expf(2.0f * x);
    return 1.0f - 2.0f / (e + 1.0f);
}
__device__ __forceinline__ float bcastlane(float v, int l) {
    return __int_as_float(__builtin_amdgcn_readlane(__float_as_int(v), l));
}

// ---------------- graph preprocessing: counting sort of edges by target ----------------

__global__ __launch_bounds__(256) void k_hist(const int* __restrict__ col,
        const float* __restrict__ w, int* __restrict__ cnt, float* __restrict__ deg) {
    int e = blockIdx.x * 256 + threadIdx.x;
    int c = col[e];
    atomicAdd(&cnt[c], 1);
    atomicAdd(&deg[c], w[e]);
}

__global__ __launch_bounds__(1024) void k_scan(const int* __restrict__ cnt,
        const float* __restrict__ deg, int* __restrict__ off, float* __restrict__ dis) {
    __shared__ int part[1024];
    int t = threadIdx.x;
    int base = t * 16;
    int loc[16];
    int sum = 0;
    #pragma unroll
    for (int i = 0; i < 16; i++) { loc[i] = sum; sum += cnt[base + i]; }
    part[t] = sum;
    __syncthreads();
    for (int ofs = 1; ofs < 1024; ofs <<= 1) {
        int add = (t >= ofs) ? part[t - ofs] : 0;
        __syncthreads();
        part[t] += add;
        __syncthreads();
    }
    int excl = part[t] - sum;
    #pragma unroll
    for (int i = 0; i < 16; i++) off[base + i] = excl + loc[i];
    if (t == 1023) off[N_NODES] = part[1023];
    #pragma unroll
    for (int i = 0; i < 16; i++) {
        float d = deg[base + i];
        dis[base + i] = (d > 0.0f) ? rsqrtf(d) : 0.0f;
    }
}

__global__ __launch_bounds__(256) void k_scatter(const int* __restrict__ row,
        const int* __restrict__ col, const float* __restrict__ w,
        const int* __restrict__ off, int* __restrict__ cur,
        const float* __restrict__ dis, int* __restrict__ srow, float* __restrict__ snorm) {
    int e = blockIdx.x * 256 + threadIdx.x;
    int c = col[e], r = row[e];
    int p = off[c] + atomicAdd(&cur[c], 1);
    srow[p] = r;
    snorm[p] = dis[r] * w[e] * dis[c];
}

// ---------------- tiled GEMM: C[M][N] = A[M][K] @ W[N][K]^T (+ b1 + b2) ----------------
// REMAP=true permutes weight rows so output col n = unit (n>>2), gate (n&3):
// gives the LSTM a [t][u][4] interleaved gate layout for one-float4-per-step loads.

template <int K, int N, bool REMAP>
__global__ __launch_bounds__(256) void k_gemm_tiled(const float* __restrict__ A,
        const float* __restrict__ W, const float* __restrict__ b1,
        const float* __restrict__ b2, float* __restrict__ C) {
    constexpr int BM = 64, BN = 128, BK = 32;
    __shared__ float sA[BK][68];    // [k][m]
    __shared__ float sW[BK][132];   // [k][n]
    int tid = threadIdx.x;
    int m0 = blockIdx.x * BM;
    int n0 = blockIdx.y * BN;
    int tr = tid >> 5;
    int tc = tid & 31;
    int lm = tid >> 3;
    int lk = (tid & 7) * 4;
    float acc[8][4] = {};
    for (int k0 = 0; k0 < K; k0 += BK) {
        #pragma unroll
        for (int p = 0; p < 2; p++) {
            int m = lm + 32 * p;
            float4 a4 = *(const float4*)&A[(size_t)(m0 + m) * K + k0 + lk];
            sA[lk + 0][m] = a4.x; sA[lk + 1][m] = a4.y;
            sA[lk + 2][m] = a4.z; sA[lk + 3][m] = a4.w;
        }
        #pragma unroll
        for (int p = 0; p < 4; p++) {
            int n = lm + 32 * p;
            int nn = n0 + n;
            int wrow = REMAP ? (((nn & 3) << 6) | (nn >> 2)) : nn;
            float4 w4 = *(const float4*)&W[(size_t)wrow * K + k0 + lk];
            sW[lk + 0][n] = w4.x; sW[lk + 1][n] = w4.y;
            sW[lk + 2][n] = w4.z; sW[lk + 3][n] = w4.w;
        }
        __syncthreads();
        #pragma unroll
        for (int kk = 0; kk < BK; kk++) {
            float4 a0 = *(const float4*)&sA[kk][tr * 8];
            float4 a1 = *(const float4*)&sA[kk][tr * 8 + 4];
            float4 b4 = *(const float4*)&sW[kk][tc * 4];
            float av[8] = {a0.x, a0.y, a0.z, a0.w, a1.x, a1.y, a1.z, a1.w};
            float bv[4] = {b4.x, b4.y, b4.z, b4.w};
            #pragma unroll
            for (int i = 0; i < 8; i++)
                #pragma unroll
                for (int j = 0; j < 4; j++)
                    acc[i][j] += av[i] * bv[j];
        }
        __syncthreads();
    }
    int cb = n0 + tc * 4;
    float badd[4] = {0.f, 0.f, 0.f, 0.f};
    #pragma unroll
    for (int j = 0; j < 4; j++) {
        int colr = cb + j;
        int brow = REMAP ? (((colr & 3) << 6) | (colr >> 2)) : colr;
        if (b1) badd[j] += b1[brow];
        if (b2) badd[j] += b2[brow];
    }
    #pragma unroll
    for (int i = 0; i < 8; i++) {
        size_t r = (size_t)(m0 + tr * 8 + i);
        float4 v = {acc[i][0] + badd[0], acc[i][1] + badd[1],
                    acc[i][2] + badd[2], acc[i][3] + badd[3]};
        *(float4*)&C[r * N + cb] = v;
    }
}

// ---------------- GCN aggregation: one wave per target node, float2 per lane ----------------

__global__ __launch_bounds__(256) void k_conv(const float* __restrict__ xl,
        const int* __restrict__ srow, const float* __restrict__ snorm,
        const int* __restrict__ off, const float* __restrict__ bias,
        float* __restrict__ out) {
    int wv = threadIdx.x >> 6, l = threadIdx.x & 63;
    int n = blockIdx.x * 4 + wv;
    int p0 = off[n], p1 = off[n + 1];
    const float2* x2 = (const float2*)xl;
    float ax0 = 0.f, ay0 = 0.f, ax1 = 0.f, ay1 = 0.f;
    int p = p0;
    for (; p + 2 <= p1; p += 2) {
        int r0 = srow[p], r1 = srow[p + 1];
        float m0 = snorm[p], m1 = snorm[p + 1];
        float2 v0 = x2[(size_t)r0 * 64 + l];
        float2 v1 = x2[(size_t)r1 * 64 + l];
        ax0 += m0 * v0.x; ay0 += m0 * v0.y;
        ax1 += m1 * v1.x; ay1 += m1 * v1.y;
    }
    if (p < p1) {
        int r0 = srow[p];
        float m0 = snorm[p];
        float2 v0 = x2[(size_t)r0 * 64 + l];
        ax0 += m0 * v0.x; ay0 += m0 * v0.y;
    }
    float2 bb = ((const float2*)bias)[l];
    float2 res;
    res.x = fmaxf(ax0 + ax1 + bb.x, 0.0f);
    res.y = fmaxf(ay0 + ay1 + bb.y, 0.0f);
    ((float2*)out)[(size_t)n * 64 + l] = res;
}

// ---------------- chunked bidirectional LSTM ----------------
// 256 workgroups x 256 threads; each wave = one chunk, 4 chunks/wg all same
// direction. Lane u owns unit u. wi/wf rows in VGPR (128 regs, no AGPR
// pressure); wg/wo rows in LDS (32KB, shared by the 4 waves, b128 broadcast-
// friendly [k4][g2][u] layout). h broadcast via v_readlane. Gate pre-acts in
// [t][u][4] layout -> ONE coalesced dwordx4 per step, prefetched 4 deep.

#define LSTM_LOADG(G)                                                           \
    {                                                                           \
        int tt = tload < 0 ? 0 : (tload > N_NODES - 1 ? N_NODES - 1 : tload);   \
        G = *(const float4*)(gpre + (size_t)tt * 256 + u * 4);                  \
        tload += tstep;                                                         \
    }

#define LSTM_STEP(G)                                                            \
    {                                                                           \
        float si = G.x, sf = G.y, sg = G.z, so = G.w;                           \
        float si2 = 0.f, sf2 = 0.f, sg2 = 0.f, so2 = 0.f;                       \
        _Pragma("unroll")                                                       \
        for (int k4 = 0; k4 < 16; k4++) {                                       \
            float4 wg4 = s_wgo[k4][0][u];                                       \
            float4 wo4 = s_wgo[k4][1][u];                                       \
            float h0 = bcastlane(h, 4 * k4 + 0);                                \
            float h1 = bcastlane(h, 4 * k4 + 1);                                \
            float h2 = bcastlane(h, 4 * k4 + 2);                                \
            float h3 = bcastlane(h, 4 * k4 + 3);                                \
            si  += wi[4 * k4 + 0] * h0; sf  += wf[4 * k4 + 0] * h0;             \
            sg  += wg4.x * h0;          so  += wo4.x * h0;                      \
            si2 += wi[4 * k4 + 1] * h1; sf2 += wf[4 * k4 + 1] * h1;             \
            sg2 += wg4.y * h1;          so2 += wo4.y * h1;                      \
            si  += wi[4 * k4 + 2] * h2; sf  += wf[4 * k4 + 2] * h2;             \
            sg  += wg4.z * h2;          so  += wo4.z * h2;                      \
            si2 += wi[4 * k4 + 3] * h3; sf2 += wf[4 * k4 + 3] * h3;             \
            sg2 += wg4.w * h3;          so2 += wo4.w * h3;                      \
        }                                                                       \
        float iv = sigm_f(si + si2);                                            \
        float fv = sigm_f(sf + sf2);                                            \
        float gv = tanh_f(sg + sg2);                                            \
        float ov = sigm_f(so + so2);                                            \
        c = fv * c + iv * gv;                                                   \
        h = ov * tanh_f(c);                                                     \
        unsigned rel = (unsigned)(tcur - outLo);                                \
        if (rel < S_CHUNK) hout[(size_t)tcur * 64 + u] = h;                     \
        tcur += tstep;                                                          \
    }

__global__ __launch_bounds__(256, 1) void k_lstm(const float* __restrict__ gpf,
        const float* __restrict__ gpb, const float* __restrict__ Whh_f,
        const float* __restrict__ Whh_b, float* __restrict__ hf, float* __restrict__ hb) {
    __shared__ float4 s_wgo[16][2][64];       // [k4][gate g/o][unit] = 32 KB
    int wg = blockIdx.x;
    int dir = wg >> 7;
    int wv = threadIdx.x >> 6;
    int u = threadIdx.x & 63;
    int ch = (wg & 127) * 4 + wv;
    const float* gpre = dir ? gpb : gpf;
    const float* Whh = dir ? Whh_b : Whh_f;
    float* hout = dir ? hb : hf;
    const float4* Wr4 = (const float4*)Whh;   // [256 rows][16 float4]
    // cooperative fill of the g/o weight LDS tile (rows 128..255)
    #pragma unroll
    for (int j = 0; j < 8; j++) {
        int flat = j * 256 + threadIdx.x;     // 0..2047
        int r = flat >> 4;                    // 0..127
        int k4 = flat & 15;
        s_wgo[k4][r >> 6][r & 63] = Wr4[(size_t)(128 + r) * 16 + k4];
    }
    // per-lane i/f rows into VGPRs
    float wi[64], wf[64];
    #pragma unroll
    for (int k4 = 0; k4 < 16; k4++) {
        float4 a = Wr4[(size_t)u * 16 + k4];
        wi[4*k4+0] = a.x; wi[4*k4+1] = a.y; wi[4*k4+2] = a.z; wi[4*k4+3] = a.w;
        float4 b = Wr4[(size_t)(64 + u) * 16 + k4];
        wf[4*k4+0] = b.x; wf[4*k4+1] = b.y; wf[4*k4+2] = b.z; wf[4*k4+3] = b.w;
    }
    __syncthreads();
    int outLo = ch * S_CHUNK;
    int tstart, nsteps, tstep;
    if (dir == 0) {
        int t0 = outLo - WARMUP; if (t0 < 0) t0 = 0;
        tstart = t0; nsteps = outLo + S_CHUNK - t0; tstep = 1;
    } else {
        int t1 = outLo + S_CHUNK - 1 + WARMUP; if (t1 > N_NODES - 1) t1 = N_NODES - 1;
        tstart = t1; nsteps = t1 - outLo + 1; tstep = -1;
    }
    int tload = tstart, tcur = tstart;
    float4 G0, G1, G2, G3;
    LSTM_LOADG(G0); LSTM_LOADG(G1); LSTM_LOADG(G2); LSTM_LOADG(G3);
    float c = 0.0f, h = 0.0f;
    for (int s = 0; s < nsteps; s += 4) {
        LSTM_STEP(G0); LSTM_LOADG(G0);
        LSTM_STEP(G1); LSTM_LOADG(G1);
        LSTM_STEP(G2); LSTM_LOADG(G2);
        LSTM_STEP(G3); LSTM_LOADG(G3);
    }
}

// ---------------- output layer ----------------

__global__ __launch_bounds__(256) void k_final(const float* __restrict__ hf,
        const float* __restrict__ hb, const float* __restrict__ Wl,
        const float* __restrict__ bl, float* __restrict__ out) {
    int i = blockIdx.x * 256 + threadIdx.x;
    const float4* hfp = (const float4*)(hf + (size_t)i * 64);
    const float4* hbp = (const float4*)(hb + (size_t)i * 64);
    float acc = bl[0];
    #pragma unroll
    for (int k = 0; k < 16; k++) {
        float4 h4 = hfp[k];
        float4 w4 = *(const float4*)&Wl[k * 4];
        acc += h4.x * w4.x + h4.y * w4.y + h4.z * w4.z + h4.w * w4.w;
    }
    #pragma unroll
    for (int k = 0; k < 16; k++) {
        float4 h4 = hbp[k];
        float4 w4 = *(const float4*)&Wl[64 + k * 4];
        acc += h4.x * w4.x + h4.y * w4.y + h4.z * w4.z + h4.w * w4.w;
    }
    out[i] = 1.0f / (1.0f + __expf(-acc));
}

extern "C" void kernel_launch(void* const* d_in, const int* in_sizes, int n_in,
                              void* d_out, int out_size, void* d_ws, size_t ws_size,
                              hipStream_t stream) {
    const float* x     = (const float*)d_in[0];
    const int*   ei    = (const int*)d_in[1];
    const float* ew    = (const float*)d_in[2];
    const float* W1    = (const float*)d_in[3];
    const float* b1    = (const float*)d_in[4];
    const float* W2    = (const float*)d_in[5];
    const float* b2    = (const float*)d_in[6];
    const float* Wih_f = (const float*)d_in[7];
    const float* Whh_f = (const float*)d_in[8];
    const float* bih_f = (const float*)d_in[9];
    const float* bhh_f = (const float*)d_in[10];
    const float* Wih_b = (const float*)d_in[11];
    const float* Whh_b = (const float*)d_in[12];
    const float* bih_b = (const float*)d_in[13];
    const float* bhh_b = (const float*)d_in[14];
    const float* Wl    = (const float*)d_in[15];
    const float* bl    = (const float*)d_in[16];
    const int* erow = ei;            // edge_index[0] = source
    const int* ecol = ei + N_EDGES;  // edge_index[1] = target

    float* ws = (float*)d_ws;
    size_t o = 0;
    auto alloc = [&](size_t n) { float* p = ws + o; o += n; return p; };
    float* xl    = alloc((size_t)N_NODES * 128);   // GEMM outputs (pre-aggregation)
    float* hbuf  = alloc((size_t)N_NODES * 128);   // conv outputs
    float* gpf   = alloc((size_t)N_NODES * 256);   // [t][u][4] gate pre-acts, fwd
    float* gpb   = alloc((size_t)N_NODES * 256);
    float* hf    = alloc((size_t)N_NODES * 64);
    float* hb    = alloc((size_t)N_NODES * 64);
    float* deg   = alloc(N_NODES);                 // deg,cnt,cur contiguous: one memset
    int*   cnt   = (int*)alloc(N_NODES);
    int*   cur   = (int*)alloc(N_NODES);
    float* dis   = alloc(N_NODES);
    int*   off   = (int*)alloc(N_NODES + 4);
    int*   srow  = (int*)alloc(N_EDGES);
    float* snorm = alloc(N_EDGES);
    (void)o; (void)ws_size; (void)in_sizes; (void)n_in; (void)out_size;

    hipMemsetAsync(deg, 0, (size_t)N_NODES * 4 * 3, stream);
    k_hist<<<N_EDGES / 256, 256, 0, stream>>>(ecol, ew, cnt, deg);
    k_scan<<<1, 1024, 0, stream>>>(cnt, deg, off, dis);
    k_scatter<<<N_EDGES / 256, 256, 0, stream>>>(erow, ecol, ew, off, cur, dis, srow, snorm);
    k_gemm_tiled<768, 128, false><<<dim3(N_NODES / 64, 1), 256, 0, stream>>>(x, W1, nullptr, nullptr, xl);
    k_conv<<<N_NODES / 4, 256, 0, stream>>>(xl, srow, snorm, off, b1, hbuf);
    k_gemm_tiled<128, 128, false><<<dim3(N_NODES / 64, 1), 256, 0, stream>>>(hbuf, W2, nullptr, nullptr, xl);
    k_conv<<<N_NODES / 4, 256, 0, stream>>>(xl, srow, snorm, off, b2, hbuf);
    k_gemm_tiled<128, 256, true><<<dim3(N_NODES / 64, 2), 256, 0, stream>>>(hbuf, Wih_f, bih_f, bhh_f, gpf);
    k_gemm_tiled<128, 256, true><<<dim3(N_NODES / 64, 2), 256, 0, stream>>>(hbuf, Wih_b, bih_b, bhh_b, gpb);
    k_lstm<<<256, 256, 0, stream>>>(gpf, gpb, Whh_f, Whh_b, hf, hb);
    k_final<<<N_NODES / 256, 256, 0, stream>>>(hf, hb, Wl, bl, (float*)d_out);
}